// Round 1
// baseline (8274.503 us; speedup 1.0000x reference)
//
#include <hip/hip_runtime.h>

typedef _Float16 f16;
typedef _Float16 f16x2 __attribute__((ext_vector_type(2)));
typedef _Float16 f16x8 __attribute__((ext_vector_type(8)));
typedef float    f32x4 __attribute__((ext_vector_type(4)));

#if defined(__has_builtin)
#if __has_builtin(__builtin_amdgcn_fdot2)
#define HAVE_FDOT2 1
#endif
#endif

#ifdef HAVE_FDOT2
#define FDOT2(a, b, c) __builtin_amdgcn_fdot2((a), (b), (c), false)
#else
static __device__ __forceinline__ float FDOT2(f16x2 a, f16x2 b, float c) {
  return c + (float)a[0] * (float)b[0] + (float)a[1] * (float)b[1];
}
#endif

static __device__ __forceinline__ f16x2 asf16x2(unsigned int v) {
  return __builtin_bit_cast(f16x2, v);
}

struct PtrPack { const float* p[8]; };

// ---------------- prep: 8x (256x256) fp32 [k][u] -> f16 [u-col][k], LDS transpose ----
__global__ __launch_bounds__(256) void k_prep(PtrPack pp, f16* __restrict__ wxT,
                                              f16* __restrict__ whT) {
  int m = blockIdx.z, kt = blockIdx.y, ut = blockIdx.x;
  const float* src = pp.p[m];
  f16* dst = (m < 4) ? (wxT + m * 65536) : (whT + (m - 4) * 65536);
  __shared__ f16 tile[64][66];
  int c = threadIdx.x & 63, r0 = threadIdx.x >> 6;
#pragma unroll
  for (int i = 0; i < 16; ++i) {
    int r = i * 4 + r0;
    tile[c][r] = (f16)src[(kt * 64 + r) * 256 + ut * 64 + c];  // tile[u_local][k_local]
  }
  __syncthreads();
#pragma unroll
  for (int i = 0; i < 16; ++i) {
    int ul = i * 4 + r0;
    dst[(size_t)(ut * 64 + ul) * 256 + kt * 64 + c] = tile[ul][c];
  }
}

// ---------------- X-part GEMM: XW[t][b][col] (f16) = X[b,t,:] @ Wx[:,col] ------------
// tile: 64 rows (time) x 256 cols, 4 waves, K=256 in 8 steps of 32.
__global__ __launch_bounds__(256) void k_gemm(const float* __restrict__ X,
                                              const f16* __restrict__ wxT,
                                              f16* __restrict__ xw, int chunk0) {
  int nblk = blockIdx.x;  // 0..3  (cols n0 = nblk*256)
  int mblk = blockIdx.y;  // rows within chunk
  int b    = blockIdx.z;  // batch
  __shared__ f16 Alds[64][48];
  __shared__ f16 Blds[256][48];
  int tid = threadIdx.x, wave = tid >> 6, lane = tid & 63;
  int l15 = lane & 15, l4 = lane >> 4;
  f32x4 acc[16];
#pragma unroll
  for (int i = 0; i < 16; ++i) acc[i] = (f32x4){0.f, 0.f, 0.f, 0.f};
  const float* Xb = X + ((size_t)b * 2048 + chunk0 + mblk * 64) * 256;
  const f16*   Bb = wxT + (size_t)nblk * 256 * 256;
  int arow = tid >> 2, akq = (tid & 3) * 8;

  for (int kk = 0; kk < 8; ++kk) {
    {  // stage A: 64x32 fp32 -> f16
      const float* s = Xb + arow * 256 + kk * 32 + akq;
      float4 v0 = *(const float4*)s;
      float4 v1 = *(const float4*)(s + 4);
      union { f16 h[8]; uint4 q; } u;
      u.h[0] = (f16)v0.x; u.h[1] = (f16)v0.y; u.h[2] = (f16)v0.z; u.h[3] = (f16)v0.w;
      u.h[4] = (f16)v1.x; u.h[5] = (f16)v1.y; u.h[6] = (f16)v1.z; u.h[7] = (f16)v1.w;
      *(uint4*)(&Alds[arow][akq]) = u.q;
    }
    {  // stage B: 256 cols x 32 k (f16, already [col][k])
      const uint4* s = (const uint4*)(Bb + (size_t)tid * 256 + kk * 32);
      uint4* d = (uint4*)(&Blds[tid][0]);
      d[0] = s[0]; d[1] = s[1]; d[2] = s[2]; d[3] = s[3];
    }
    __syncthreads();
    f16x8 a = *(const f16x8*)(&Alds[wave * 16 + l15][l4 * 8]);
#pragma unroll
    for (int nt = 0; nt < 16; ++nt) {
      f16x8 bb = *(const f16x8*)(&Blds[nt * 16 + l15][l4 * 8]);
      acc[nt] = __builtin_amdgcn_mfma_f32_16x16x32_f16(a, bb, acc[nt], 0, 0, 0);
    }
    __syncthreads();
  }
#pragma unroll
  for (int nt = 0; nt < 16; ++nt) {
#pragma unroll
    for (int r = 0; r < 4; ++r) {
      int trow = mblk * 64 + wave * 16 + l4 * 4 + r;
      int col  = nblk * 256 + nt * 16 + l15;
      xw[((size_t)trow * 64 + b) * 1024 + col] = (f16)acc[nt][r];
    }
  }
}

// ---------------- recurrent kernel: 1 wg per batch, unit-per-thread ------------------
// gates i,f,g weights in VGPRs (384), o-gate in LDS; h broadcast via LDS f16; c in reg.
__global__ __launch_bounds__(256, 1) void k_rnn(
    const f16* __restrict__ xw, const f16* __restrict__ whT,
    const float* __restrict__ bi, const float* __restrict__ bf_,
    const float* __restrict__ bg, const float* __restrict__ bo,
    float* __restrict__ out, float* __restrict__ hstate, float* __restrict__ cstate,
    int chunk0, int chunk_len) {
  extern __shared__ char smem[];
  uint4* WL = (uint4*)smem;                                   // [32][256] o-gate weights
  unsigned short* hb = (unsigned short*)(smem + 32 * 256 * 16);  // [2][256] h as f16
  int b = blockIdx.x, u = threadIdx.x;

  const uint4* wi = (const uint4*)(whT + (size_t)(0 * 256 + u) * 256);
  const uint4* wf = (const uint4*)(whT + (size_t)(1 * 256 + u) * 256);
  const uint4* wg = (const uint4*)(whT + (size_t)(2 * 256 + u) * 256);
  const uint4* wo = (const uint4*)(whT + (size_t)(3 * 256 + u) * 256);
  uint4 W0[32], W1[32], W2[32];
#pragma unroll
  for (int k = 0; k < 32; ++k) {
    W0[k] = wi[k]; W1[k] = wf[k]; W2[k] = wg[k];
    WL[k * 256 + u] = wo[k];
  }
  float B0 = bi[u], B1 = bf_[u], B2 = bg[u], B3 = bo[u];

  float c, h;
  if (chunk0 == 0) { c = 0.f; h = 0.f; }
  else { c = cstate[b * 256 + u]; h = hstate[b * 256 + u]; }
  hb[u] = __builtin_bit_cast(unsigned short, (f16)h);
  __syncthreads();

  int p = 0;
  for (int t = 0; t < chunk_len; ++t) {
    const f16* xwt = xw + ((size_t)t * 64 + b) * 1024 + u;
    float x0 = (float)xwt[0], x1 = (float)xwt[256], x2 = (float)xwt[512], x3 = (float)xwt[768];
    float a0 = 0.f, a1 = 0.f, a2 = 0.f, a3 = 0.f;
    const uint4* hq = (const uint4*)(hb + p * 256);
#pragma unroll
    for (int k = 0; k < 32; ++k) {
      uint4 h4 = hq[k];        // broadcast: 8 h values (f16)
      uint4 w3 = WL[k * 256 + u];
      a0 = FDOT2(asf16x2(h4.x), asf16x2(W0[k].x), a0);
      a1 = FDOT2(asf16x2(h4.x), asf16x2(W1[k].x), a1);
      a2 = FDOT2(asf16x2(h4.x), asf16x2(W2[k].x), a2);
      a3 = FDOT2(asf16x2(h4.x), asf16x2(w3.x), a3);
      a0 = FDOT2(asf16x2(h4.y), asf16x2(W0[k].y), a0);
      a1 = FDOT2(asf16x2(h4.y), asf16x2(W1[k].y), a1);
      a2 = FDOT2(asf16x2(h4.y), asf16x2(W2[k].y), a2);
      a3 = FDOT2(asf16x2(h4.y), asf16x2(w3.y), a3);
      a0 = FDOT2(asf16x2(h4.z), asf16x2(W0[k].z), a0);
      a1 = FDOT2(asf16x2(h4.z), asf16x2(W1[k].z), a1);
      a2 = FDOT2(asf16x2(h4.z), asf16x2(W2[k].z), a2);
      a3 = FDOT2(asf16x2(h4.z), asf16x2(w3.z), a3);
      a0 = FDOT2(asf16x2(h4.w), asf16x2(W0[k].w), a0);
      a1 = FDOT2(asf16x2(h4.w), asf16x2(W1[k].w), a1);
      a2 = FDOT2(asf16x2(h4.w), asf16x2(W2[k].w), a2);
      a3 = FDOT2(asf16x2(h4.w), asf16x2(w3.w), a3);
    }
    a0 += x0 + B0; a1 += x1 + B1; a2 += x2 + B2; a3 += x3 + B3;
    float gi = 1.f / (1.f + __expf(-a0));
    float gf = 1.f / (1.f + __expf(-a1));
    float e2 = __expf(-2.f * fabsf(a2));
    float gg = copysignf((1.f - e2) / (1.f + e2), a2);
    float go = 1.f / (1.f + __expf(-a3));
    c = gf * c + gi * gg;
    float ec = __expf(-2.f * fabsf(c));
    float tc = copysignf((1.f - ec) / (1.f + ec), c);
    h = go * tc;
    int gt = chunk0 + t;
    out[((size_t)b * 2048 + gt) * 256 + u] = h;
    hb[(p ^ 1) * 256 + u] = __builtin_bit_cast(unsigned short, (f16)h);
    if (gt == 2047) {
      out[33554432 + b * 256 + u] = h;
      out[33554432 + 16384 + b * 256 + u] = c;
    }
    __syncthreads();
    p ^= 1;
  }
  if (chunk0 + chunk_len < 2048) {
    hstate[b * 256 + u] = h;
    cstate[b * 256 + u] = c;
  }
}

extern "C" void kernel_launch(void* const* d_in, const int* in_sizes, int n_in,
                              void* d_out, int out_size, void* d_ws, size_t ws_size,
                              hipStream_t stream) {
  const float* X = (const float*)d_in[0];
  // dict order: X, W_ii, W_hi, b_i, W_if, W_hf, b_f, W_ig, W_hg, b_g, W_io, W_ho, b_o
  PtrPack pp;
  pp.p[0] = (const float*)d_in[1];   // W_ii
  pp.p[1] = (const float*)d_in[4];   // W_if
  pp.p[2] = (const float*)d_in[7];   // W_ig
  pp.p[3] = (const float*)d_in[10];  // W_io
  pp.p[4] = (const float*)d_in[2];   // W_hi
  pp.p[5] = (const float*)d_in[5];   // W_hf
  pp.p[6] = (const float*)d_in[8];   // W_hg
  pp.p[7] = (const float*)d_in[11];  // W_ho
  const float* bi  = (const float*)d_in[3];
  const float* bf_ = (const float*)d_in[6];
  const float* bg  = (const float*)d_in[9];
  const float* bo  = (const float*)d_in[12];
  float* out = (float*)d_out;

  char* ws = (char*)d_ws;
  f16*   wxT    = (f16*)ws;                       // 524288 B
  f16*   whT    = (f16*)(ws + 524288);            // 524288 B
  float* hstate = (float*)(ws + 1048576);         // 65536 B
  float* cstate = (float*)(ws + 1114112);         // 65536 B
  f16*   xwbuf  = (f16*)(ws + 1179648);           // S_c * 64 * 1024 * 2 B

  // adaptive chunk length (multiple of 64)
  long avail = (ws_size > 1310720) ? (long)(ws_size - 1310720) : 0;
  long sc = avail / 131072;   // bytes per step of XW (f16)
  sc = (sc / 64) * 64;
  if (sc < 64) sc = 64;       // assume ws is at least ~19 MB
  if (sc > 2048) sc = 2048;

  static const int RNN_SMEM = 32 * 256 * 16 + 2 * 256 * 2;
  hipFuncSetAttribute((const void*)k_rnn, hipFuncAttributeMaxDynamicSharedMemorySize,
                      RNN_SMEM);

  k_prep<<<dim3(4, 4, 8), 256, 0, stream>>>(pp, wxT, whT);

  for (int s0 = 0; s0 < 2048; s0 += (int)sc) {
    int len = (int)((2048 - s0) < sc ? (2048 - s0) : sc);
    k_gemm<<<dim3(4, len / 64, 64), 256, 0, stream>>>(X, wxT, xwbuf, s0);
    k_rnn<<<dim3(64), 256, RNN_SMEM, stream>>>(xwbuf, whT, bi, bf_, bg, bo, out,
                                               hstate, cstate, s0, len);
  }
}

// Round 2
// 3371.441 us; speedup vs baseline: 2.4543x; 2.4543x over previous
//
#include <hip/hip_runtime.h>

typedef _Float16 f16;
typedef _Float16 f16x2 __attribute__((ext_vector_type(2)));
typedef _Float16 f16x8 __attribute__((ext_vector_type(8)));
typedef float    f32x4 __attribute__((ext_vector_type(4)));

#if defined(__has_builtin)
#if __has_builtin(__builtin_amdgcn_fdot2)
#define HAVE_FDOT2 1
#endif
#endif

#ifdef HAVE_FDOT2
#define FDOT2(a, b, c) __builtin_amdgcn_fdot2((a), (b), (c), false)
#else
static __device__ __forceinline__ float FDOT2(f16x2 a, f16x2 b, float c) {
  return c + (float)a[0] * (float)b[0] + (float)a[1] * (float)b[1];
}
#endif

static __device__ __forceinline__ f16x2 asf16x2(unsigned int v) {
  return __builtin_bit_cast(f16x2, v);
}

struct PtrPack { const float* p[8]; };

// ---------------- prep: 8x (256x256) fp32 [k][u] -> f16 [u-col][k], LDS transpose ----
__global__ __launch_bounds__(256) void k_prep(PtrPack pp, f16* __restrict__ wxT,
                                              f16* __restrict__ whT) {
  int m = blockIdx.z, kt = blockIdx.y, ut = blockIdx.x;
  const float* src = pp.p[m];
  f16* dst = (m < 4) ? (wxT + m * 65536) : (whT + (m - 4) * 65536);
  __shared__ f16 tile[64][66];
  int c = threadIdx.x & 63, r0 = threadIdx.x >> 6;
#pragma unroll
  for (int i = 0; i < 16; ++i) {
    int r = i * 4 + r0;
    tile[c][r] = (f16)src[(kt * 64 + r) * 256 + ut * 64 + c];  // tile[u_local][k_local]
  }
  __syncthreads();
#pragma unroll
  for (int i = 0; i < 16; ++i) {
    int ul = i * 4 + r0;
    dst[(size_t)(ut * 64 + ul) * 256 + kt * 64 + c] = tile[ul][c];
  }
}

// ---------------- X-part GEMM: XW[t][b][col] (f16) = X[b,t,:] @ Wx[:,col] ------------
// tile: 64 rows (time) x 256 cols, 4 waves, K=256 in 8 steps of 32.
__global__ __launch_bounds__(256) void k_gemm(const float* __restrict__ X,
                                              const f16* __restrict__ wxT,
                                              f16* __restrict__ xw, int chunk0) {
  int nblk = blockIdx.x;  // 0..3  (cols n0 = nblk*256)
  int mblk = blockIdx.y;  // rows within chunk
  int b    = blockIdx.z;  // batch
  __shared__ f16 Alds[64][48];
  __shared__ f16 Blds[256][48];
  int tid = threadIdx.x, wave = tid >> 6, lane = tid & 63;
  int l15 = lane & 15, l4 = lane >> 4;
  f32x4 acc[16];
#pragma unroll
  for (int i = 0; i < 16; ++i) acc[i] = (f32x4){0.f, 0.f, 0.f, 0.f};
  const float* Xb = X + ((size_t)b * 2048 + chunk0 + mblk * 64) * 256;
  const f16*   Bb = wxT + (size_t)nblk * 256 * 256;
  int arow = tid >> 2, akq = (tid & 3) * 8;

  for (int kk = 0; kk < 8; ++kk) {
    {  // stage A: 64x32 fp32 -> f16
      const float* s = Xb + arow * 256 + kk * 32 + akq;
      float4 v0 = *(const float4*)s;
      float4 v1 = *(const float4*)(s + 4);
      union { f16 h[8]; uint4 q; } u;
      u.h[0] = (f16)v0.x; u.h[1] = (f16)v0.y; u.h[2] = (f16)v0.z; u.h[3] = (f16)v0.w;
      u.h[4] = (f16)v1.x; u.h[5] = (f16)v1.y; u.h[6] = (f16)v1.z; u.h[7] = (f16)v1.w;
      *(uint4*)(&Alds[arow][akq]) = u.q;
    }
    {  // stage B: 256 cols x 32 k (f16, already [col][k])
      const uint4* s = (const uint4*)(Bb + (size_t)tid * 256 + kk * 32);
      uint4* d = (uint4*)(&Blds[tid][0]);
      d[0] = s[0]; d[1] = s[1]; d[2] = s[2]; d[3] = s[3];
    }
    __syncthreads();
    f16x8 a = *(const f16x8*)(&Alds[wave * 16 + l15][l4 * 8]);
#pragma unroll
    for (int nt = 0; nt < 16; ++nt) {
      f16x8 bb = *(const f16x8*)(&Blds[nt * 16 + l15][l4 * 8]);
      acc[nt] = __builtin_amdgcn_mfma_f32_16x16x32_f16(a, bb, acc[nt], 0, 0, 0);
    }
    __syncthreads();
  }
#pragma unroll
  for (int nt = 0; nt < 16; ++nt) {
#pragma unroll
    for (int r = 0; r < 4; ++r) {
      int trow = mblk * 64 + wave * 16 + l4 * 4 + r;
      int col  = nblk * 256 + nt * 16 + l15;
      xw[((size_t)trow * 64 + b) * 1024 + col] = (f16)acc[nt][r];
    }
  }
}

// ---------------- recurrent kernel: 1 wg per batch, 512 thr (unit u, k-half) --------
// gates i,f,g weights in VGPRs (192/thread), o-gate in LDS; h broadcast via LDS f16;
// k-split partials combined via LDS psum; c,h live in half==0 threads.
__global__ __launch_bounds__(512, 2) void k_rnn(
    const f16* __restrict__ xw, const f16* __restrict__ whT,
    const float* __restrict__ bi, const float* __restrict__ bf_,
    const float* __restrict__ bg, const float* __restrict__ bo,
    float* __restrict__ out, float* __restrict__ hstate, float* __restrict__ cstate,
    int chunk0, int chunk_len) {
  extern __shared__ char smem[];
  uint4* WO = (uint4*)smem;                                   // [32][256] o-gate (128KB)
  float4* psum = (float4*)(smem + 131072);                    // [256] partials (4KB)
  unsigned short* hb = (unsigned short*)(smem + 135168);      // [2][256] h as f16 (1KB)
  int b = blockIdx.x;
  int u = threadIdx.x & 255;
  int half = threadIdx.x >> 8;  // k in [half*128, half*128+128) -- wave-uniform

  // in-register weights for gates i,f,g (this thread's k-half): 48 uint4 = 192 VGPR
  const uint4* wi = (const uint4*)(whT + (size_t)(0 * 256 + u) * 256 + half * 128);
  const uint4* wf = (const uint4*)(whT + (size_t)(1 * 256 + u) * 256 + half * 128);
  const uint4* wg = (const uint4*)(whT + (size_t)(2 * 256 + u) * 256 + half * 128);
  const uint4* wo = (const uint4*)(whT + (size_t)(3 * 256 + u) * 256 + half * 128);
  uint4 Wi[16], Wf[16], Wg[16];
#pragma unroll
  for (int j = 0; j < 16; ++j) {
    Wi[j] = wi[j]; Wf[j] = wf[j]; Wg[j] = wg[j];
    WO[(half * 16 + j) * 256 + u] = wo[j];  // interleaved [kk][u] -> conflict-free
  }
  float B0 = bi[u], B1 = bf_[u], B2 = bg[u], B3 = bo[u];

  float c, h;
  if (chunk0 == 0) { c = 0.f; h = 0.f; }
  else { c = cstate[b * 256 + u]; h = hstate[b * 256 + u]; }
  if (!half) hb[u] = __builtin_bit_cast(unsigned short, (f16)h);
  __syncthreads();

  int p = 0;
  for (int t = 0; t < chunk_len; ++t) {
    float x0 = 0.f, x1 = 0.f, x2 = 0.f, x3 = 0.f;
    if (!half) {  // wave-uniform branch; loads issue early, hide under dot loop
      const f16* xwt = xw + ((size_t)t * 64 + b) * 1024 + u;
      x0 = (float)xwt[0]; x1 = (float)xwt[256]; x2 = (float)xwt[512]; x3 = (float)xwt[768];
    }
    const uint4* hq = (const uint4*)(hb + p * 256) + half * 16;
    float a0 = 0.f, a1 = 0.f, a2 = 0.f, a3 = 0.f;
#pragma unroll
    for (int j = 0; j < 16; ++j) {
      uint4 h4 = hq[j];                    // broadcast: 8 h values (f16)
      uint4 w3 = WO[(half * 16 + j) * 256 + u];
      a0 = FDOT2(asf16x2(h4.x), asf16x2(Wi[j].x), a0);
      a1 = FDOT2(asf16x2(h4.x), asf16x2(Wf[j].x), a1);
      a2 = FDOT2(asf16x2(h4.x), asf16x2(Wg[j].x), a2);
      a3 = FDOT2(asf16x2(h4.x), asf16x2(w3.x), a3);
      a0 = FDOT2(asf16x2(h4.y), asf16x2(Wi[j].y), a0);
      a1 = FDOT2(asf16x2(h4.y), asf16x2(Wf[j].y), a1);
      a2 = FDOT2(asf16x2(h4.y), asf16x2(Wg[j].y), a2);
      a3 = FDOT2(asf16x2(h4.y), asf16x2(w3.y), a3);
      a0 = FDOT2(asf16x2(h4.z), asf16x2(Wi[j].z), a0);
      a1 = FDOT2(asf16x2(h4.z), asf16x2(Wf[j].z), a1);
      a2 = FDOT2(asf16x2(h4.z), asf16x2(Wg[j].z), a2);
      a3 = FDOT2(asf16x2(h4.z), asf16x2(w3.z), a3);
      a0 = FDOT2(asf16x2(h4.w), asf16x2(Wi[j].w), a0);
      a1 = FDOT2(asf16x2(h4.w), asf16x2(Wf[j].w), a1);
      a2 = FDOT2(asf16x2(h4.w), asf16x2(Wg[j].w), a2);
      a3 = FDOT2(asf16x2(h4.w), asf16x2(w3.w), a3);
    }
    if (half) {
      psum[u] = (float4){a0, a1, a2, a3};
    }
    __syncthreads();
    if (!half) {
      float4 ps = psum[u];
      a0 += ps.x + x0 + B0;
      a1 += ps.y + x1 + B1;
      a2 += ps.z + x2 + B2;
      a3 += ps.w + x3 + B3;
      float gi = 1.f / (1.f + __expf(-a0));
      float gf = 1.f / (1.f + __expf(-a1));
      float e2 = __expf(-2.f * fabsf(a2));
      float gg = copysignf((1.f - e2) / (1.f + e2), a2);
      float go = 1.f / (1.f + __expf(-a3));
      c = gf * c + gi * gg;
      float ec = __expf(-2.f * fabsf(c));
      float tc = copysignf((1.f - ec) / (1.f + ec), c);
      h = go * tc;
      int gt = chunk0 + t;
      out[((size_t)b * 2048 + gt) * 256 + u] = h;
      hb[(p ^ 1) * 256 + u] = __builtin_bit_cast(unsigned short, (f16)h);
      if (gt == 2047) {
        out[33554432 + b * 256 + u] = h;
        out[33554432 + 16384 + b * 256 + u] = c;
      }
    }
    __syncthreads();
    p ^= 1;
  }
  if ((chunk0 + chunk_len < 2048) && !half) {
    hstate[b * 256 + u] = h;
    cstate[b * 256 + u] = c;
  }
}

extern "C" void kernel_launch(void* const* d_in, const int* in_sizes, int n_in,
                              void* d_out, int out_size, void* d_ws, size_t ws_size,
                              hipStream_t stream) {
  const float* X = (const float*)d_in[0];
  // dict order: X, W_ii, W_hi, b_i, W_if, W_hf, b_f, W_ig, W_hg, b_g, W_io, W_ho, b_o
  PtrPack pp;
  pp.p[0] = (const float*)d_in[1];   // W_ii
  pp.p[1] = (const float*)d_in[4];   // W_if
  pp.p[2] = (const float*)d_in[7];   // W_ig
  pp.p[3] = (const float*)d_in[10];  // W_io
  pp.p[4] = (const float*)d_in[2];   // W_hi
  pp.p[5] = (const float*)d_in[5];   // W_hf
  pp.p[6] = (const float*)d_in[8];   // W_hg
  pp.p[7] = (const float*)d_in[11];  // W_ho
  const float* bi  = (const float*)d_in[3];
  const float* bf_ = (const float*)d_in[6];
  const float* bg  = (const float*)d_in[9];
  const float* bo  = (const float*)d_in[12];
  float* out = (float*)d_out;

  char* ws = (char*)d_ws;
  f16*   wxT    = (f16*)ws;                       // 524288 B
  f16*   whT    = (f16*)(ws + 524288);            // 524288 B
  float* hstate = (float*)(ws + 1048576);         // 65536 B
  float* cstate = (float*)(ws + 1114112);         // 65536 B
  f16*   xwbuf  = (f16*)(ws + 1179648);           // S_c * 64 * 1024 * 2 B

  // adaptive chunk length (multiple of 64)
  long avail = (ws_size > 1310720) ? (long)(ws_size - 1310720) : 0;
  long sc = avail / 131072;   // bytes per step of XW (f16)
  sc = (sc / 64) * 64;
  if (sc < 64) sc = 64;       // assume ws is at least ~19 MB
  if (sc > 2048) sc = 2048;

  static const int RNN_SMEM = 131072 + 4096 + 1024;
  hipFuncSetAttribute((const void*)k_rnn, hipFuncAttributeMaxDynamicSharedMemorySize,
                      RNN_SMEM);

  k_prep<<<dim3(4, 4, 8), 256, 0, stream>>>(pp, wxT, whT);

  for (int s0 = 0; s0 < 2048; s0 += (int)sc) {
    int len = (int)((2048 - s0) < sc ? (2048 - s0) : sc);
    k_gemm<<<dim3(4, len / 64, 64), 256, 0, stream>>>(X, wxT, xwbuf, s0);
    k_rnn<<<dim3(64), 512, RNN_SMEM, stream>>>(xwbuf, whT, bi, bf_, bg, bo, out,
                                               hstate, cstate, s0, len);
  }
}

// Round 3
// 3326.435 us; speedup vs baseline: 2.4875x; 1.0135x over previous
//
#include <hip/hip_runtime.h>

typedef _Float16 f16;
typedef _Float16 f16x2 __attribute__((ext_vector_type(2)));
typedef _Float16 f16x8 __attribute__((ext_vector_type(8)));
typedef float    f32x4 __attribute__((ext_vector_type(4)));
typedef unsigned int u32x4 __attribute__((ext_vector_type(4)));

#if defined(__has_builtin)
#if __has_builtin(__builtin_amdgcn_fdot2)
#define HAVE_FDOT2 1
#endif
#endif

#ifdef HAVE_FDOT2
#define FDOT2(a, b, c) __builtin_amdgcn_fdot2((a), (b), (c), false)
#else
static __device__ __forceinline__ float FDOT2(f16x2 a, f16x2 b, float c) {
  return c + (float)a[0] * (float)b[0] + (float)a[1] * (float)b[1];
}
#endif

static __device__ __forceinline__ f16x2 asf16x2(unsigned int v) {
  return __builtin_bit_cast(f16x2, v);
}

struct PtrPack { const float* p[8]; };

// ---------------- prep: 8x (256x256) fp32 [k][u] -> f16 [u-col][k], LDS transpose ----
__global__ __launch_bounds__(256) void k_prep(PtrPack pp, f16* __restrict__ wxT,
                                              f16* __restrict__ whT) {
  int m = blockIdx.z, kt = blockIdx.y, ut = blockIdx.x;
  const float* src = pp.p[m];
  f16* dst = (m < 4) ? (wxT + m * 65536) : (whT + (m - 4) * 65536);
  __shared__ f16 tile[64][66];
  int c = threadIdx.x & 63, r0 = threadIdx.x >> 6;
#pragma unroll
  for (int i = 0; i < 16; ++i) {
    int r = i * 4 + r0;
    tile[c][r] = (f16)src[(kt * 64 + r) * 256 + ut * 64 + c];  // tile[u_local][k_local]
  }
  __syncthreads();
#pragma unroll
  for (int i = 0; i < 16; ++i) {
    int ul = i * 4 + r0;
    dst[(size_t)(ut * 64 + ul) * 256 + kt * 64 + c] = tile[ul][c];
  }
}

// ---------------- X-part GEMM: XW[t][b][col] (f16) = X[b,t,:] @ Wx[:,col] ------------
// tile: 64 rows (time) x 256 cols, 4 waves, K=256 in 8 steps of 32.
__global__ __launch_bounds__(256) void k_gemm(const float* __restrict__ X,
                                              const f16* __restrict__ wxT,
                                              f16* __restrict__ xw, int chunk0) {
  int nblk = blockIdx.x;  // 0..3  (cols n0 = nblk*256)
  int mblk = blockIdx.y;  // rows within chunk
  int b    = blockIdx.z;  // batch
  __shared__ f16 Alds[64][48];
  __shared__ f16 Blds[256][48];
  int tid = threadIdx.x, wave = tid >> 6, lane = tid & 63;
  int l15 = lane & 15, l4 = lane >> 4;
  f32x4 acc[16];
#pragma unroll
  for (int i = 0; i < 16; ++i) acc[i] = (f32x4){0.f, 0.f, 0.f, 0.f};
  const float* Xb = X + ((size_t)b * 2048 + chunk0 + mblk * 64) * 256;
  const f16*   Bb = wxT + (size_t)nblk * 256 * 256;
  int arow = tid >> 2, akq = (tid & 3) * 8;

  for (int kk = 0; kk < 8; ++kk) {
    {  // stage A: 64x32 fp32 -> f16
      const float* s = Xb + arow * 256 + kk * 32 + akq;
      float4 v0 = *(const float4*)s;
      float4 v1 = *(const float4*)(s + 4);
      union { f16 h[8]; uint4 q; } u;
      u.h[0] = (f16)v0.x; u.h[1] = (f16)v0.y; u.h[2] = (f16)v0.z; u.h[3] = (f16)v0.w;
      u.h[4] = (f16)v1.x; u.h[5] = (f16)v1.y; u.h[6] = (f16)v1.z; u.h[7] = (f16)v1.w;
      *(uint4*)(&Alds[arow][akq]) = u.q;
    }
    {  // stage B: 256 cols x 32 k (f16, already [col][k])
      const uint4* s = (const uint4*)(Bb + (size_t)tid * 256 + kk * 32);
      uint4* d = (uint4*)(&Blds[tid][0]);
      d[0] = s[0]; d[1] = s[1]; d[2] = s[2]; d[3] = s[3];
    }
    __syncthreads();
    f16x8 a = *(const f16x8*)(&Alds[wave * 16 + l15][l4 * 8]);
#pragma unroll
    for (int nt = 0; nt < 16; ++nt) {
      f16x8 bb = *(const f16x8*)(&Blds[nt * 16 + l15][l4 * 8]);
      acc[nt] = __builtin_amdgcn_mfma_f32_16x16x32_f16(a, bb, acc[nt], 0, 0, 0);
    }
    __syncthreads();
  }
#pragma unroll
  for (int nt = 0; nt < 16; ++nt) {
#pragma unroll
    for (int r = 0; r < 4; ++r) {
      int trow = mblk * 64 + wave * 16 + l4 * 4 + r;
      int col  = nblk * 256 + nt * 16 + l15;
      xw[((size_t)trow * 64 + b) * 1024 + col] = (f16)acc[nt][r];
    }
  }
}

// ---------------- recurrent kernel: 1 wg per batch, 512 thr (unit u, k-half) --------
// gates i,f,g weights pinned in VGPRs via VOLATILE loads (prevents the compiler from
// sinking the loop-invariant loads into the t-loop, which is what killed R2: VGPR=128
// meant 48 re-loads/thread/step). o-gate in LDS; h broadcast via LDS f16.
__global__ __launch_bounds__(512, 2) void k_rnn(
    const f16* __restrict__ xw, const f16* __restrict__ whT,
    const float* __restrict__ bi, const float* __restrict__ bf_,
    const float* __restrict__ bg, const float* __restrict__ bo,
    float* __restrict__ out, float* __restrict__ hstate, float* __restrict__ cstate,
    int chunk0, int chunk_len) {
  extern __shared__ char smem[];
  u32x4* WO = (u32x4*)smem;                                   // [32][256] o-gate (128KB)
  float4* psum = (float4*)(smem + 131072);                    // [256] partials (4KB)
  unsigned short* hb = (unsigned short*)(smem + 135168);      // [2][256] h as f16 (1KB)
  int b = blockIdx.x;
  int u = threadIdx.x & 255;
  int half = threadIdx.x >> 8;  // k in [half*128, half*128+128) -- wave-uniform

  // o-gate -> LDS, interleaved [kk][u] (conflict-free b128)
  const u32x4* wo = (const u32x4*)(whT + (size_t)(3 * 256 + u) * 256 + half * 128);
#pragma unroll
  for (int j = 0; j < 16; ++j) WO[(half * 16 + j) * 256 + u] = wo[j];

  // gates i,f,g: VOLATILE loads -> values must stay live across the t-loop (192 VGPR)
  const volatile u32x4* wi =
      (const volatile u32x4*)(whT + (size_t)(0 * 256 + u) * 256 + half * 128);
  const volatile u32x4* wf =
      (const volatile u32x4*)(whT + (size_t)(1 * 256 + u) * 256 + half * 128);
  const volatile u32x4* wg =
      (const volatile u32x4*)(whT + (size_t)(2 * 256 + u) * 256 + half * 128);
  u32x4 Wi[16], Wf[16], Wg[16];
#pragma unroll
  for (int j = 0; j < 16; ++j) { Wi[j] = wi[j]; Wf[j] = wf[j]; Wg[j] = wg[j]; }

  float B0 = bi[u], B1 = bf_[u], B2 = bg[u], B3 = bo[u];

  float c, h;
  if (chunk0 == 0) { c = 0.f; h = 0.f; }
  else { c = cstate[b * 256 + u]; h = hstate[b * 256 + u]; }
  if (!half) hb[u] = __builtin_bit_cast(unsigned short, (f16)h);
  __syncthreads();

  int p = 0;
#pragma unroll 1
  for (int t = 0; t < chunk_len; ++t) {
    float x0 = 0.f, x1 = 0.f, x2 = 0.f, x3 = 0.f;
    if (!half) {  // wave-uniform branch; loads issue early, hide under dot loop
      const f16* xwt = xw + ((size_t)t * 64 + b) * 1024 + u;
      x0 = (float)xwt[0]; x1 = (float)xwt[256]; x2 = (float)xwt[512]; x3 = (float)xwt[768];
    }
    const u32x4* hq = (const u32x4*)(hb + p * 256) + half * 16;
    float a0 = 0.f, a1 = 0.f, a2 = 0.f, a3 = 0.f;
#pragma unroll
    for (int j = 0; j < 16; ++j) {
      u32x4 h4 = hq[j];                    // broadcast: 8 h values (f16)
      u32x4 w3 = WO[(half * 16 + j) * 256 + u];
      a0 = FDOT2(asf16x2(h4.x), asf16x2(Wi[j].x), a0);
      a1 = FDOT2(asf16x2(h4.x), asf16x2(Wf[j].x), a1);
      a2 = FDOT2(asf16x2(h4.x), asf16x2(Wg[j].x), a2);
      a3 = FDOT2(asf16x2(h4.x), asf16x2(w3.x), a3);
      a0 = FDOT2(asf16x2(h4.y), asf16x2(Wi[j].y), a0);
      a1 = FDOT2(asf16x2(h4.y), asf16x2(Wf[j].y), a1);
      a2 = FDOT2(asf16x2(h4.y), asf16x2(Wg[j].y), a2);
      a3 = FDOT2(asf16x2(h4.y), asf16x2(w3.y), a3);
      a0 = FDOT2(asf16x2(h4.z), asf16x2(Wi[j].z), a0);
      a1 = FDOT2(asf16x2(h4.z), asf16x2(Wf[j].z), a1);
      a2 = FDOT2(asf16x2(h4.z), asf16x2(Wg[j].z), a2);
      a3 = FDOT2(asf16x2(h4.z), asf16x2(w3.z), a3);
      a0 = FDOT2(asf16x2(h4.w), asf16x2(Wi[j].w), a0);
      a1 = FDOT2(asf16x2(h4.w), asf16x2(Wf[j].w), a1);
      a2 = FDOT2(asf16x2(h4.w), asf16x2(Wg[j].w), a2);
      a3 = FDOT2(asf16x2(h4.w), asf16x2(w3.w), a3);
    }
    if (half) {
      psum[u] = (float4){a0, a1, a2, a3};
    }
    __syncthreads();
    if (!half) {
      float4 ps = psum[u];
      a0 += ps.x + x0 + B0;
      a1 += ps.y + x1 + B1;
      a2 += ps.z + x2 + B2;
      a3 += ps.w + x3 + B3;
      float gi = 1.f / (1.f + __expf(-a0));
      float gf = 1.f / (1.f + __expf(-a1));
      float e2 = __expf(-2.f * fabsf(a2));
      float gg = copysignf((1.f - e2) / (1.f + e2), a2);
      float go = 1.f / (1.f + __expf(-a3));
      c = gf * c + gi * gg;
      float ec = __expf(-2.f * fabsf(c));
      float tc = copysignf((1.f - ec) / (1.f + ec), c);
      h = go * tc;
      int gt = chunk0 + t;
      out[((size_t)b * 2048 + gt) * 256 + u] = h;
      hb[(p ^ 1) * 256 + u] = __builtin_bit_cast(unsigned short, (f16)h);
      if (gt == 2047) {
        out[33554432 + b * 256 + u] = h;
        out[33554432 + 16384 + b * 256 + u] = c;
      }
    }
    __syncthreads();
    p ^= 1;
  }
  if ((chunk0 + chunk_len < 2048) && !half) {
    hstate[b * 256 + u] = h;
    cstate[b * 256 + u] = c;
  }
}

extern "C" void kernel_launch(void* const* d_in, const int* in_sizes, int n_in,
                              void* d_out, int out_size, void* d_ws, size_t ws_size,
                              hipStream_t stream) {
  const float* X = (const float*)d_in[0];
  // dict order: X, W_ii, W_hi, b_i, W_if, W_hf, b_f, W_ig, W_hg, b_g, W_io, W_ho, b_o
  PtrPack pp;
  pp.p[0] = (const float*)d_in[1];   // W_ii
  pp.p[1] = (const float*)d_in[4];   // W_if
  pp.p[2] = (const float*)d_in[7];   // W_ig
  pp.p[3] = (const float*)d_in[10];  // W_io
  pp.p[4] = (const float*)d_in[2];   // W_hi
  pp.p[5] = (const float*)d_in[5];   // W_hf
  pp.p[6] = (const float*)d_in[8];   // W_hg
  pp.p[7] = (const float*)d_in[11];  // W_ho
  const float* bi  = (const float*)d_in[3];
  const float* bf_ = (const float*)d_in[6];
  const float* bg  = (const float*)d_in[9];
  const float* bo  = (const float*)d_in[12];
  float* out = (float*)d_out;

  char* ws = (char*)d_ws;
  f16*   wxT    = (f16*)ws;                       // 524288 B
  f16*   whT    = (f16*)(ws + 524288);            // 524288 B
  float* hstate = (float*)(ws + 1048576);         // 65536 B
  float* cstate = (float*)(ws + 1114112);         // 65536 B
  f16*   xwbuf  = (f16*)(ws + 1179648);           // S_c * 64 * 1024 * 2 B

  // adaptive chunk length (multiple of 64)
  long avail = (ws_size > 1310720) ? (long)(ws_size - 1310720) : 0;
  long sc = avail / 131072;   // bytes per step of XW (f16)
  sc = (sc / 64) * 64;
  if (sc < 64) sc = 64;       // assume ws is at least ~19 MB
  if (sc > 2048) sc = 2048;

  static const int RNN_SMEM = 131072 + 4096 + 1024;
  hipFuncSetAttribute((const void*)k_rnn, hipFuncAttributeMaxDynamicSharedMemorySize,
                      RNN_SMEM);

  k_prep<<<dim3(4, 4, 8), 256, 0, stream>>>(pp, wxT, whT);

  for (int s0 = 0; s0 < 2048; s0 += (int)sc) {
    int len = (int)((2048 - s0) < sc ? (2048 - s0) : sc);
    k_gemm<<<dim3(4, len / 64, 64), 256, 0, stream>>>(X, wxT, xwbuf, s0);
    k_rnn<<<dim3(64), 512, RNN_SMEM, stream>>>(xwbuf, whT, bi, bf_, bg, bo, out,
                                               hstate, cstate, s0, len);
  }
}